// Round 6
// baseline (306.868 us; speedup 1.0000x reference)
//
#include <hip/hip_runtime.h>
#include <cstdint>

typedef short bf16x8 __attribute__((ext_vector_type(8)));
typedef float f32x4 __attribute__((ext_vector_type(4)));
typedef uint16_t u16x4 __attribute__((ext_vector_type(4)));

#define MFMA_16x16x32(a, b, c) __builtin_amdgcn_mfma_f32_16x16x32_bf16((a), (b), (c), 0, 0, 0)

static constexpr int BATCH = 2;
static constexpr int HEADS = 12;
static constexpr int NCTX  = 2048;
static constexpr int DH    = 64;
static constexpr int EMB   = 768;

// 0.125 * log2(e): Q pre-scale so softmax runs in exp2 domain
static constexpr float QSCALE = 0.125f * 1.44269504088896340736f;

// ---------- bf16 helpers (raw-bit, RN rounding) ----------
__device__ __forceinline__ uint16_t f2bf(float x) {
    uint32_t u = __float_as_uint(x);
    u += 0x7FFFu + ((u >> 16) & 1u);
    return (uint16_t)(u >> 16);
}
__device__ __forceinline__ float bf2f(uint16_t h) {
    return __uint_as_float(((uint32_t)h) << 16);
}
__device__ __forceinline__ uint32_t cvt_pk_bf16(float lo, float hi) {
    uint32_t r;
    asm("v_cvt_pk_bf16_f32 %0, %1, %2" : "=v"(r) : "v"(lo), "v"(hi));
    return r;
}

// ---------- merged Q/K split convert (blockIdx.y: 0=Q pre-scaled, 1=K) ----------
__global__ void k_splitqk(const float* __restrict__ q, const float* __restrict__ k,
                          uint16_t* __restrict__ qh, uint16_t* __restrict__ ql,
                          uint16_t* __restrict__ kh, uint16_t* __restrict__ kl, int n4) {
    int i = blockIdx.x * blockDim.x + threadIdx.x;
    if (i >= n4) return;
    const bool isK = blockIdx.y != 0;
    const float* src = isK ? k : q;
    uint16_t* hi = isK ? kh : qh;
    uint16_t* lo = isK ? kl : ql;
    const float scale = isK ? 1.0f : QSCALE;
    float4 v = reinterpret_cast<const float4*>(src)[i];
    v.x *= scale; v.y *= scale; v.z *= scale; v.w *= scale;
    uint16_t h0 = f2bf(v.x), h1 = f2bf(v.y), h2 = f2bf(v.z), h3 = f2bf(v.w);
    u16x4 hv = {h0, h1, h2, h3};
    u16x4 lv = {f2bf(v.x - bf2f(h0)), f2bf(v.y - bf2f(h1)),
                f2bf(v.z - bf2f(h2)), f2bf(v.w - bf2f(h3))};
    reinterpret_cast<u16x4*>(hi)[i] = hv;
    reinterpret_cast<u16x4*>(lo)[i] = lv;
}

// ---------- plain split (for W) ----------
__global__ void k_split(const float* __restrict__ src, uint16_t* __restrict__ hi,
                        uint16_t* __restrict__ lo, int n4) {
    int i = blockIdx.x * blockDim.x + threadIdx.x;
    if (i >= n4) return;
    float4 v = reinterpret_cast<const float4*>(src)[i];
    uint16_t h0 = f2bf(v.x), h1 = f2bf(v.y), h2 = f2bf(v.z), h3 = f2bf(v.w);
    u16x4 hv = {h0, h1, h2, h3};
    u16x4 lv = {f2bf(v.x - bf2f(h0)), f2bf(v.y - bf2f(h1)),
                f2bf(v.z - bf2f(h2)), f2bf(v.w - bf2f(h3))};
    reinterpret_cast<u16x4*>(hi)[i] = hv;
    reinterpret_cast<u16x4*>(lo)[i] = lv;
}

// ---------- V transpose+convert: [bh][n][64] fp32 -> [bh][64][n] bf16 ----------
__global__ __launch_bounds__(256) void k_vt(const float* __restrict__ v,
                                            uint16_t* __restrict__ vt) {
    const int bh = blockIdx.y;
    const int n0 = blockIdx.x * 64;
    const int t  = threadIdx.x;
    __shared__ uint16_t tileT[64][72];   // [d][n_local]

    const int r  = t >> 2;          // n-row within tile (0..63)
    const int cc = (t & 3) * 16;    // d-col base
    const float* vp = v + ((size_t)bh * NCTX + n0 + r) * DH + cc;
#pragma unroll
    for (int u = 0; u < 4; ++u) {
        float4 x = reinterpret_cast<const float4*>(vp)[u];
        tileT[cc + 4 * u + 0][r] = f2bf(x.x);
        tileT[cc + 4 * u + 1][r] = f2bf(x.y);
        tileT[cc + 4 * u + 2][r] = f2bf(x.z);
        tileT[cc + 4 * u + 3][r] = f2bf(x.w);
    }
    __syncthreads();
    const int d  = t >> 2;          // d-row (0..63)
    const int nc = (t & 3) * 16;    // n chunk
    uint16_t* op = vt + ((size_t)bh * DH + d) * NCTX + n0 + nc;
#pragma unroll
    for (int u = 0; u < 2; ++u) {
        bf16x8 x = *reinterpret_cast<const bf16x8*>(&tileT[d][nc + 8 * u]);
        *reinterpret_cast<bf16x8*>(op + 8 * u) = x;
    }
}

// ---------- flash attention ----------
// grid: (NCTX/64, BATCH*HEADS), block: 256 (4 waves). Wave owns 16 q-rows.
// K/V MFMA fragments are contiguous b128 in global (swapped-QK^T + pre-transposed
// V), so they load DIRECT from global (L1/L2-served; all 4 waves hit identical
// addresses). LDS holds only the per-wave P round-trip. One bare barrier per
// tile keeps waves loosely lockstepped for L1 sharing. Softmax/P/epilogue
// bit-identical to the proven R3/R5 kernel.
__global__ __launch_bounds__(256, 3) void k_attn(
        const uint16_t* __restrict__ qh, const uint16_t* __restrict__ ql,
        const uint16_t* __restrict__ kh, const uint16_t* __restrict__ kl,
        const uint16_t* __restrict__ vt,
        uint16_t* __restrict__ xh, uint16_t* __restrict__ xl) {
    const int bh = blockIdx.y;
    const int b  = bh / HEADS;
    const int h  = bh % HEADS;
    const int tid = threadIdx.x;
    const int w = tid >> 6;
    const int l = tid & 63;
    const int g = l >> 4;    // 16-lane group 0..3
    const int c = l & 15;

    __shared__ uint16_t P_s[4][16][72];   // [wave][q][kv]

    const int q0 = blockIdx.x * 64 + w * 16;

    // Q fragments (pre-scaled by 0.125*log2e at split time)
    const size_t qoff = ((size_t)bh * NCTX + q0 + c) * DH + 8 * g;
    bf16x8 qa_h[2], qa_l[2];
    qa_h[0] = *reinterpret_cast<const bf16x8*>(qh + qoff);
    qa_h[1] = *reinterpret_cast<const bf16x8*>(qh + qoff + 32);
    qa_l[0] = *reinterpret_cast<const bf16x8*>(ql + qoff);
    qa_l[1] = *reinterpret_cast<const bf16x8*>(ql + qoff + 32);

    // per-lane K/V fragment base pointers (advance by tile via kbase/vbase)
    const uint16_t* kfp = kh + ((size_t)bh * NCTX + c) * DH + 8 * g;
    const uint16_t* lfp = kl + ((size_t)bh * NCTX + c) * DH + 8 * g;
    const uint16_t* vfp = vt + ((size_t)bh * DH + c) * NCTX + 8 * g;

    f32x4 zero = {0.f, 0.f, 0.f, 0.f};
    f32x4 o[4] = {zero, zero, zero, zero};
    float m = -1e30f;     // running max (log2 units), per q=c (uniform across groups)
    float lsum = 0.f;     // lane-partial softmax denominator for q=c

    for (int t = 0; t < NCTX / 64; ++t) {
        __syncthreads();   // loose lockstep: keeps the 4 waves sharing L1 lines
        const int kbase = t * 64 * DH;   // element offset of this kv-tile in K
        const int vbase = t * 64;        // element offset of this kv-tile in V^T

        // ---- S^T = (K Q^T) (3-term split). s[nf][r] = S[kv=16nf+4g+r][q=c]
        f32x4 s[4] = {zero, zero, zero, zero};
        __builtin_amdgcn_s_setprio(1);
#pragma unroll
        for (int nf = 0; nf < 4; ++nf) {
#pragma unroll
            for (int kf = 0; kf < 2; ++kf) {
                bf16x8 bhf = *reinterpret_cast<const bf16x8*>(kfp + kbase + nf * 16 * DH + kf * 32);
                bf16x8 blf = *reinterpret_cast<const bf16x8*>(lfp + kbase + nf * 16 * DH + kf * 32);
                s[nf] = MFMA_16x16x32(bhf, qa_h[kf], s[nf]);
                s[nf] = MFMA_16x16x32(blf, qa_h[kf], s[nf]);
                s[nf] = MFMA_16x16x32(bhf, qa_l[kf], s[nf]);
            }
        }
        __builtin_amdgcn_s_setprio(0);

        // ---- softmax (log2 domain). Row (per-q) reduce: in-lane + 2 shfls.
        float smax = s[0][0];
#pragma unroll
        for (int nf = 0; nf < 4; ++nf)
#pragma unroll
            for (int r = 0; r < 4; ++r) smax = fmaxf(smax, s[nf][r]);
        smax = fmaxf(smax, __shfl_xor(smax, 16));
        smax = fmaxf(smax, __shfl_xor(smax, 32));

        // deferred max (THR = 11 in log2 units ~= e^8)
        if (!__all(smax <= m + 11.0f)) {
            float mnew = fmaxf(m, smax);
            float corr = __builtin_amdgcn_exp2f(m - mnew);
            m = mnew;
            lsum *= corr;
#pragma unroll
            for (int r = 0; r < 4; ++r) {
                float cr = __shfl(corr, 4 * g + r);   // corr for q-local 4g+r
#pragma unroll
                for (int f = 0; f < 4; ++f) o[f][r] *= cr;
            }
        }

        // p = exp2(s - m); pack pairs and write 4 contiguous kv per lane (b64)
#pragma unroll
        for (int nf = 0; nf < 4; ++nf) {
            float p0 = __builtin_amdgcn_exp2f(s[nf][0] - m);
            float p1 = __builtin_amdgcn_exp2f(s[nf][1] - m);
            float p2 = __builtin_amdgcn_exp2f(s[nf][2] - m);
            float p3 = __builtin_amdgcn_exp2f(s[nf][3] - m);
            lsum += (p0 + p1) + (p2 + p3);
            uint2 pk;
            pk.x = cvt_pk_bf16(p0, p1);
            pk.y = cvt_pk_bf16(p2, p3);
            *reinterpret_cast<uint2*>(&P_s[w][c][16 * nf + 4 * g]) = pk;
        }

        // ---- O += P V (V fragments direct from global; contiguous b128)
        bf16x8 pa0 = *reinterpret_cast<const bf16x8*>(&P_s[w][c][8 * g]);
        bf16x8 pa1 = *reinterpret_cast<const bf16x8*>(&P_s[w][c][32 + 8 * g]);
        __builtin_amdgcn_s_setprio(1);
#pragma unroll
        for (int f = 0; f < 4; ++f) {
            bf16x8 b0 = *reinterpret_cast<const bf16x8*>(vfp + vbase + f * 16 * NCTX);
            bf16x8 b1 = *reinterpret_cast<const bf16x8*>(vfp + vbase + f * 16 * NCTX + 32);
            o[f] = MFMA_16x16x32(pa0, b0, o[f]);
            o[f] = MFMA_16x16x32(pa1, b1, o[f]);
        }
        __builtin_amdgcn_s_setprio(0);
    }

    // ---- epilogue: reduce l over the 4 groups, normalize, split, store
    lsum += __shfl_xor(lsum, 16);
    lsum += __shfl_xor(lsum, 32);
    const float linv = 1.0f / lsum;

    const size_t xbase = ((size_t)b * NCTX + q0) * EMB + h * DH;
#pragma unroll
    for (int r = 0; r < 4; ++r) {
        float lr = __shfl(linv, 4 * g + r);   // 1/l for q-local 4g+r
#pragma unroll
        for (int f = 0; f < 4; ++f) {
            float v = o[f][r] * lr;
            uint16_t hv = f2bf(v);
            uint16_t lv2 = f2bf(v - bf2f(hv));
            size_t addr = xbase + (size_t)(4 * g + r) * EMB + f * 16 + c;
            xh[addr] = hv;
            xl[addr] = lv2;
        }
    }
}

// ---------- projection GEMM: Y[4096x768] = X @ W^T + bias (3-term split) ----------
// R3 barrier skeleton + clamped-index register prefetch (no conditionals, no
// uninitialized values): next k-step W/X loads issue before the MFMA cluster.
__global__ __launch_bounds__(256) void k_proj(
        const uint16_t* __restrict__ xh, const uint16_t* __restrict__ xl,
        const uint16_t* __restrict__ wh, const uint16_t* __restrict__ wl,
        const float* __restrict__ bias, float* __restrict__ out) {
    const int tid = threadIdx.x;
    const int w = tid >> 6;
    const int l = tid & 63;
    const int g = l >> 4;
    const int c = l & 15;
    const int m0 = blockIdx.x * 64 + w * 16;
    const int n0 = blockIdx.y * 64;

    __shared__ uint16_t Wh_s[64][40];
    __shared__ uint16_t Wl_s[64][40];

    f32x4 zero = {0.f, 0.f, 0.f, 0.f};
    f32x4 acc[4] = {zero, zero, zero, zero};

    const int srow = tid >> 2;   // 0..63
    const int sch  = tid & 3;    // 0..3
    constexpr int KSTEPS = EMB / 32;   // 24

    const uint16_t* whp = wh + (size_t)(n0 + srow) * EMB + sch * 8;
    const uint16_t* wlp = wl + (size_t)(n0 + srow) * EMB + sch * 8;
    const uint16_t* xhp = xh + (size_t)(m0 + c) * EMB + 8 * g;
    const uint16_t* xlp = xl + (size_t)(m0 + c) * EMB + 8 * g;

    // prologue loads (k-step 0)
    bf16x8 wldh = *reinterpret_cast<const bf16x8*>(whp);
    bf16x8 wldl = *reinterpret_cast<const bf16x8*>(wlp);
    bf16x8 ah   = *reinterpret_cast<const bf16x8*>(xhp);
    bf16x8 al   = *reinterpret_cast<const bf16x8*>(xlp);

    for (int ks = 0; ks < KSTEPS; ++ks) {
        __syncthreads();     // previous iteration's readers are done (no-op at ks=0)
        *reinterpret_cast<bf16x8*>(&Wh_s[srow][sch * 8]) = wldh;
        *reinterpret_cast<bf16x8*>(&Wl_s[srow][sch * 8]) = wldl;
        __syncthreads();     // stores visible to all waves

        // prefetch next k-step (clamped on the last iteration: re-reads k-step
        // KSTEPS-1; values are dead after the final loop trip — always in-bounds)
        const int ksn = (ks + 1 < KSTEPS) ? (ks + 1) : (KSTEPS - 1);
        bf16x8 wldh_n = *reinterpret_cast<const bf16x8*>(whp + (size_t)ksn * 32);
        bf16x8 wldl_n = *reinterpret_cast<const bf16x8*>(wlp + (size_t)ksn * 32);
        bf16x8 ah_n   = *reinterpret_cast<const bf16x8*>(xhp + (size_t)ksn * 32);
        bf16x8 al_n   = *reinterpret_cast<const bf16x8*>(xlp + (size_t)ksn * 32);

        __builtin_amdgcn_s_setprio(1);
#pragma unroll
        for (int nf = 0; nf < 4; ++nf) {
            bf16x8 bhf = *reinterpret_cast<const bf16x8*>(&Wh_s[nf * 16 + c][8 * g]);
            bf16x8 blf = *reinterpret_cast<const bf16x8*>(&Wl_s[nf * 16 + c][8 * g]);
            acc[nf] = MFMA_16x16x32(ah, bhf, acc[nf]);
            acc[nf] = MFMA_16x16x32(al, bhf, acc[nf]);
            acc[nf] = MFMA_16x16x32(ah, blf, acc[nf]);
        }
        __builtin_amdgcn_s_setprio(0);

        wldh = wldh_n; wldl = wldl_n; ah = ah_n; al = al_n;
    }

#pragma unroll
    for (int nf = 0; nf < 4; ++nf) {
#pragma unroll
        for (int r = 0; r < 4; ++r) {
            int row = m0 + g * 4 + r;
            int col = n0 + nf * 16 + c;
            out[(size_t)row * EMB + col] = acc[nf][r] + bias[col];
        }
    }
}

extern "C" void kernel_launch(void* const* d_in, const int* in_sizes, int n_in,
                              void* d_out, int out_size, void* d_ws, size_t ws_size,
                              hipStream_t stream) {
    const float* q    = (const float*)d_in[0];
    const float* k    = (const float*)d_in[1];
    const float* v    = (const float*)d_in[2];
    const float* pw   = (const float*)d_in[3];
    const float* pb   = (const float*)d_in[4];
    float* out = (float*)d_out;

    const size_t nqkv = (size_t)BATCH * HEADS * NCTX * DH;   // 3,145,728
    const size_t nx   = (size_t)BATCH * NCTX * EMB;          // 3,145,728
    const size_t nw   = (size_t)EMB * EMB;                   //   589,824

    uint8_t* ws = (uint8_t*)d_ws;
    uint16_t* qh = (uint16_t*)ws;              ws += nqkv * 2;
    uint16_t* ql = (uint16_t*)ws;              ws += nqkv * 2;
    uint16_t* kh = (uint16_t*)ws;              ws += nqkv * 2;
    uint16_t* kl = (uint16_t*)ws;              ws += nqkv * 2;
    uint16_t* vt = (uint16_t*)ws;              ws += nqkv * 2;
    uint16_t* xh = (uint16_t*)ws;              ws += nx * 2;
    uint16_t* xl = (uint16_t*)ws;              ws += nx * 2;
    uint16_t* wh = (uint16_t*)ws;              ws += nw * 2;
    uint16_t* wl = (uint16_t*)ws;              ws += nw * 2;

    // converts (Q pre-scaled by 0.125*log2e; merged Q/K launch)
    k_splitqk<<<dim3((int)(nqkv / 4 / 256), 2), 256, 0, stream>>>(
        q, k, qh, ql, kh, kl, (int)(nqkv / 4));
    k_split<<<(int)(nw / 4 / 256), 256, 0, stream>>>(pw, wh, wl, (int)(nw / 4));
    k_vt<<<dim3(NCTX / 64, BATCH * HEADS), 256, 0, stream>>>(v, vt);

    // attention (direct-from-cache K/V fragments, P-only LDS)
    k_attn<<<dim3(NCTX / 64, BATCH * HEADS), 256, 0, stream>>>(qh, ql, kh, kl, vt, xh, xl);

    // projection
    k_proj<<<dim3((BATCH * NCTX) / 64, EMB / 64), 256, 0, stream>>>(xh, xl, wh, wl, pb, out);
}

// Round 7
// 84.327 us; speedup vs baseline: 3.6390x; 3.6390x over previous
//
#include <hip/hip_runtime.h>
#include <cstdint>

typedef short bf16x8 __attribute__((ext_vector_type(8)));
typedef float f32x4 __attribute__((ext_vector_type(4)));
typedef uint16_t u16x4 __attribute__((ext_vector_type(4)));

#define MFMA_16x16x32(a, b, c) __builtin_amdgcn_mfma_f32_16x16x32_bf16((a), (b), (c), 0, 0, 0)

static constexpr int BATCH = 2;
static constexpr int HEADS = 12;
static constexpr int NCTX  = 2048;
static constexpr int DH    = 64;
static constexpr int EMB   = 768;

// 0.125 * log2(e): Q pre-scale so softmax runs in exp2 domain
static constexpr float QSCALE = 0.125f * 1.44269504088896340736f;

// ---------- bf16 helpers (raw-bit, RN rounding) ----------
__device__ __forceinline__ uint16_t f2bf(float x) {
    uint32_t u = __float_as_uint(x);
    u += 0x7FFFu + ((u >> 16) & 1u);
    return (uint16_t)(u >> 16);
}
__device__ __forceinline__ uint32_t cvt_pk_bf16(float lo, float hi) {
    uint32_t r;
    asm("v_cvt_pk_bf16_f32 %0, %1, %2" : "=v"(r) : "v"(lo), "v"(hi));
    return r;
}

// ---------- merged Q/K convert (blockIdx.y: 0=Q pre-scaled, 1=K) ----------
__global__ void k_cvtqk(const float* __restrict__ q, const float* __restrict__ k,
                        uint16_t* __restrict__ qb, uint16_t* __restrict__ kb, int n4) {
    int i = blockIdx.x * blockDim.x + threadIdx.x;
    if (i >= n4) return;
    const bool isK = blockIdx.y != 0;
    const float* src = isK ? k : q;
    uint16_t* dst = isK ? kb : qb;
    const float scale = isK ? 1.0f : QSCALE;
    float4 v = reinterpret_cast<const float4*>(src)[i];
    u16x4 hv = {f2bf(v.x * scale), f2bf(v.y * scale), f2bf(v.z * scale), f2bf(v.w * scale)};
    reinterpret_cast<u16x4*>(dst)[i] = hv;
}

// ---------- plain convert (for W) ----------
__global__ void k_cvt(const float* __restrict__ src, uint16_t* __restrict__ dst, int n4) {
    int i = blockIdx.x * blockDim.x + threadIdx.x;
    if (i >= n4) return;
    float4 v = reinterpret_cast<const float4*>(src)[i];
    u16x4 hv = {f2bf(v.x), f2bf(v.y), f2bf(v.z), f2bf(v.w)};
    reinterpret_cast<u16x4*>(dst)[i] = hv;
}

// ---------- V transpose+convert: [bh][n][64] fp32 -> [bh][64][n] bf16 ----------
__global__ __launch_bounds__(256) void k_vt(const float* __restrict__ v,
                                            uint16_t* __restrict__ vt) {
    const int bh = blockIdx.y;
    const int n0 = blockIdx.x * 64;
    const int t  = threadIdx.x;
    __shared__ uint16_t tileT[64][72];   // [d][n_local]

    const int r  = t >> 2;          // n-row within tile (0..63)
    const int cc = (t & 3) * 16;    // d-col base
    const float* vp = v + ((size_t)bh * NCTX + n0 + r) * DH + cc;
#pragma unroll
    for (int u = 0; u < 4; ++u) {
        float4 x = reinterpret_cast<const float4*>(vp)[u];
        tileT[cc + 4 * u + 0][r] = f2bf(x.x);
        tileT[cc + 4 * u + 1][r] = f2bf(x.y);
        tileT[cc + 4 * u + 2][r] = f2bf(x.z);
        tileT[cc + 4 * u + 3][r] = f2bf(x.w);
    }
    __syncthreads();
    const int d  = t >> 2;          // d-row (0..63)
    const int nc = (t & 3) * 16;    // n chunk
    uint16_t* op = vt + ((size_t)bh * DH + d) * NCTX + n0 + nc;
#pragma unroll
    for (int u = 0; u < 2; ++u) {
        bf16x8 x = *reinterpret_cast<const bf16x8*>(&tileT[d][nc + 8 * u]);
        *reinterpret_cast<bf16x8*>(op + 8 * u) = x;
    }
}

// ---------- flash attention ----------
// grid: (NCTX/64, BATCH*HEADS), block: 256 (4 waves). Wave owns 16 q-rows.
// R5 structure minus all lo-terms: single-bf16 QK^T (softmax's sqrt(sum p^2)
// damping makes the Markidis split unnecessary — see R6 error model).
// Swapped QK^T, exp2 domain, deferred max, reg-prefetch staging.
__global__ __launch_bounds__(256) void k_attn(
        const uint16_t* __restrict__ qb, const uint16_t* __restrict__ kb,
        const uint16_t* __restrict__ vt, uint16_t* __restrict__ xb) {
    const int bh = blockIdx.y;
    const int b  = bh / HEADS;
    const int h  = bh % HEADS;
    const int tid = threadIdx.x;
    const int w = tid >> 6;
    const int l = tid & 63;
    const int g = l >> 4;    // 16-lane group 0..3
    const int c = l & 15;

    __shared__ uint16_t Kh_s[64][72];
    __shared__ uint16_t Vt_s[64][72];     // [d][kv]
    __shared__ uint16_t P_s [4][16][72];  // [wave][q][kv]

    const int q0 = blockIdx.x * 64 + w * 16;

    // Q fragments (pre-scaled by 0.125*log2e at convert time)
    const size_t qoff = ((size_t)bh * NCTX + q0 + c) * DH + 8 * g;
    bf16x8 qa[2];
    qa[0] = *reinterpret_cast<const bf16x8*>(qb + qoff);
    qa[1] = *reinterpret_cast<const bf16x8*>(qb + qoff + 32);

    f32x4 zero = {0.f, 0.f, 0.f, 0.f};
    f32x4 o[4] = {zero, zero, zero, zero};
    float m = -1e30f;     // running max (log2 units), per q=c (uniform across groups)
    float lsum = 0.f;     // lane-partial softmax denominator for q=c

    // staging decomposition: 256 thr -> 32 rows x 8 chunks, two row-passes
    const int srow = tid >> 3;      // 0..31
    const int sch  = tid & 7;       // 0..7

    const uint16_t* kb_b = kb + (size_t)bh * NCTX * DH + srow * DH + sch * 8;
    const uint16_t* vt_b = vt + (size_t)bh * DH * NCTX + srow * NCTX + sch * 8;

    // prologue: stage tile 0
    {
        bf16x8 a0 = *reinterpret_cast<const bf16x8*>(kb_b);
        bf16x8 a1 = *reinterpret_cast<const bf16x8*>(kb_b + 32 * DH);
        bf16x8 v0 = *reinterpret_cast<const bf16x8*>(vt_b);
        bf16x8 v1 = *reinterpret_cast<const bf16x8*>(vt_b + 32 * NCTX);
        *reinterpret_cast<bf16x8*>(&Kh_s[srow][sch * 8])      = a0;
        *reinterpret_cast<bf16x8*>(&Kh_s[srow + 32][sch * 8]) = a1;
        *reinterpret_cast<bf16x8*>(&Vt_s[srow][sch * 8])      = v0;
        *reinterpret_cast<bf16x8*>(&Vt_s[srow + 32][sch * 8]) = v1;
    }
    __syncthreads();

    for (int t = 0; t < NCTX / 64; ++t) {
        // issue next-tile loads early (hide latency under compute)
        bf16x8 nk0, nk1, nv0, nv1;
        const bool pf = (t + 1) < NCTX / 64;
        if (pf) {
            const size_t ko = (size_t)(t + 1) * 64 * DH;
            const size_t vo = (size_t)(t + 1) * 64;
            nk0 = *reinterpret_cast<const bf16x8*>(kb_b + ko);
            nk1 = *reinterpret_cast<const bf16x8*>(kb_b + ko + 32 * DH);
            nv0 = *reinterpret_cast<const bf16x8*>(vt_b + vo);
            nv1 = *reinterpret_cast<const bf16x8*>(vt_b + vo + 32 * NCTX);
        }

        // ---- S^T = (K Q^T) single-bf16. s[nf][r] = S[kv=16nf+4g+r][q=c]
        f32x4 s[4] = {zero, zero, zero, zero};
        __builtin_amdgcn_s_setprio(1);
#pragma unroll
        for (int nf = 0; nf < 4; ++nf) {
#pragma unroll
            for (int kf = 0; kf < 2; ++kf) {
                bf16x8 bhf = *reinterpret_cast<const bf16x8*>(&Kh_s[nf * 16 + c][kf * 32 + 8 * g]);
                s[nf] = MFMA_16x16x32(bhf, qa[kf], s[nf]);
            }
        }
        __builtin_amdgcn_s_setprio(0);

        // ---- softmax (log2 domain). Row (per-q) reduce: in-lane + 2 shfls.
        float smax = s[0][0];
#pragma unroll
        for (int nf = 0; nf < 4; ++nf)
#pragma unroll
            for (int r = 0; r < 4; ++r) smax = fmaxf(smax, s[nf][r]);
        smax = fmaxf(smax, __shfl_xor(smax, 16));
        smax = fmaxf(smax, __shfl_xor(smax, 32));

        // deferred max (THR = 11 in log2 units ~= e^8)
        if (!__all(smax <= m + 11.0f)) {
            float mnew = fmaxf(m, smax);
            float corr = __builtin_amdgcn_exp2f(m - mnew);
            m = mnew;
            lsum *= corr;
#pragma unroll
            for (int r = 0; r < 4; ++r) {
                float cr = __shfl(corr, 4 * g + r);   // corr for q-local 4g+r
#pragma unroll
                for (int f = 0; f < 4; ++f) o[f][r] *= cr;
            }
        }

        // p = exp2(s - m); pack pairs and write 4 contiguous kv per lane (b64)
#pragma unroll
        for (int nf = 0; nf < 4; ++nf) {
            float p0 = __builtin_amdgcn_exp2f(s[nf][0] - m);
            float p1 = __builtin_amdgcn_exp2f(s[nf][1] - m);
            float p2 = __builtin_amdgcn_exp2f(s[nf][2] - m);
            float p3 = __builtin_amdgcn_exp2f(s[nf][3] - m);
            lsum += (p0 + p1) + (p2 + p3);
            uint2 pk;
            pk.x = cvt_pk_bf16(p0, p1);
            pk.y = cvt_pk_bf16(p2, p3);
            *reinterpret_cast<uint2*>(&P_s[w][c][16 * nf + 4 * g]) = pk;
        }

        // ---- O += P V (Vt_s gives contiguous B-fragments)
        bf16x8 pa0 = *reinterpret_cast<const bf16x8*>(&P_s[w][c][8 * g]);
        bf16x8 pa1 = *reinterpret_cast<const bf16x8*>(&P_s[w][c][32 + 8 * g]);
        __builtin_amdgcn_s_setprio(1);
#pragma unroll
        for (int f = 0; f < 4; ++f) {
            bf16x8 b0 = *reinterpret_cast<const bf16x8*>(&Vt_s[f * 16 + c][8 * g]);
            bf16x8 b1 = *reinterpret_cast<const bf16x8*>(&Vt_s[f * 16 + c][32 + 8 * g]);
            o[f] = MFMA_16x16x32(pa0, b0, o[f]);
            o[f] = MFMA_16x16x32(pa1, b1, o[f]);
        }
        __builtin_amdgcn_s_setprio(0);

        __syncthreads();   // all waves done reading this tile
        if (pf) {
            *reinterpret_cast<bf16x8*>(&Kh_s[srow][sch * 8])      = nk0;
            *reinterpret_cast<bf16x8*>(&Kh_s[srow + 32][sch * 8]) = nk1;
            *reinterpret_cast<bf16x8*>(&Vt_s[srow][sch * 8])      = nv0;
            *reinterpret_cast<bf16x8*>(&Vt_s[srow + 32][sch * 8]) = nv1;
        }
        __syncthreads();   // next tile visible
    }

    // ---- epilogue: reduce l over the 4 groups, normalize, store bf16
    lsum += __shfl_xor(lsum, 16);
    lsum += __shfl_xor(lsum, 32);
    const float linv = 1.0f / lsum;

    const size_t xbase = ((size_t)b * NCTX + q0) * EMB + h * DH;
#pragma unroll
    for (int r = 0; r < 4; ++r) {
        float lr = __shfl(linv, 4 * g + r);   // 1/l for q-local 4g+r
#pragma unroll
        for (int f = 0; f < 4; ++f) {
            float v = o[f][r] * lr;
            size_t addr = xbase + (size_t)(4 * g + r) * EMB + f * 16 + c;
            xb[addr] = f2bf(v);
        }
    }
}

// ---------- projection GEMM: Y[4096x768] = X @ W^T + bias (single-bf16) ----------
// R5 barrier skeleton + clamped-index register prefetch.
__global__ __launch_bounds__(256) void k_proj(
        const uint16_t* __restrict__ xb, const uint16_t* __restrict__ wb,
        const float* __restrict__ bias, float* __restrict__ out) {
    const int tid = threadIdx.x;
    const int w = tid >> 6;
    const int l = tid & 63;
    const int g = l >> 4;
    const int c = l & 15;
    const int m0 = blockIdx.x * 64 + w * 16;
    const int n0 = blockIdx.y * 64;

    __shared__ uint16_t Wh_s[64][40];

    f32x4 zero = {0.f, 0.f, 0.f, 0.f};
    f32x4 acc[4] = {zero, zero, zero, zero};

    const int srow = tid >> 2;   // 0..63
    const int sch  = tid & 3;    // 0..3
    constexpr int KSTEPS = EMB / 32;   // 24

    const uint16_t* whp = wb + (size_t)(n0 + srow) * EMB + sch * 8;
    const uint16_t* xhp = xb + (size_t)(m0 + c) * EMB + 8 * g;

    // prologue loads (k-step 0)
    bf16x8 wldh = *reinterpret_cast<const bf16x8*>(whp);
    bf16x8 ah   = *reinterpret_cast<const bf16x8*>(xhp);

    for (int ks = 0; ks < KSTEPS; ++ks) {
        __syncthreads();     // previous iteration's readers are done (no-op at ks=0)
        *reinterpret_cast<bf16x8*>(&Wh_s[srow][sch * 8]) = wldh;
        __syncthreads();     // stores visible to all waves

        // prefetch next k-step (clamped on the last iteration — always in-bounds,
        // values dead after the final trip)
        const int ksn = (ks + 1 < KSTEPS) ? (ks + 1) : (KSTEPS - 1);
        bf16x8 wldh_n = *reinterpret_cast<const bf16x8*>(whp + (size_t)ksn * 32);
        bf16x8 ah_n   = *reinterpret_cast<const bf16x8*>(xhp + (size_t)ksn * 32);

        __builtin_amdgcn_s_setprio(1);
#pragma unroll
        for (int nf = 0; nf < 4; ++nf) {
            bf16x8 bhf = *reinterpret_cast<const bf16x8*>(&Wh_s[nf * 16 + c][8 * g]);
            acc[nf] = MFMA_16x16x32(ah, bhf, acc[nf]);
        }
        __builtin_amdgcn_s_setprio(0);

        wldh = wldh_n; ah = ah_n;
    }

#pragma unroll
    for (int nf = 0; nf < 4; ++nf) {
#pragma unroll
        for (int r = 0; r < 4; ++r) {
            int row = m0 + g * 4 + r;
            int col = n0 + nf * 16 + c;
            out[(size_t)row * EMB + col] = acc[nf][r] + bias[col];
        }
    }
}

extern "C" void kernel_launch(void* const* d_in, const int* in_sizes, int n_in,
                              void* d_out, int out_size, void* d_ws, size_t ws_size,
                              hipStream_t stream) {
    const float* q    = (const float*)d_in[0];
    const float* k    = (const float*)d_in[1];
    const float* v    = (const float*)d_in[2];
    const float* pw   = (const float*)d_in[3];
    const float* pb   = (const float*)d_in[4];
    float* out = (float*)d_out;

    const size_t nqkv = (size_t)BATCH * HEADS * NCTX * DH;   // 3,145,728
    const size_t nx   = (size_t)BATCH * NCTX * EMB;          // 3,145,728
    const size_t nw   = (size_t)EMB * EMB;                   //   589,824

    uint8_t* ws = (uint8_t*)d_ws;
    uint16_t* qb = (uint16_t*)ws;              ws += nqkv * 2;
    uint16_t* kb = (uint16_t*)ws;              ws += nqkv * 2;
    uint16_t* vt = (uint16_t*)ws;              ws += nqkv * 2;
    uint16_t* xb = (uint16_t*)ws;              ws += nx * 2;
    uint16_t* wb = (uint16_t*)ws;              ws += nw * 2;

    // converts (Q pre-scaled by 0.125*log2e; merged Q/K launch)
    k_cvtqk<<<dim3((int)(nqkv / 4 / 256), 2), 256, 0, stream>>>(
        q, k, qb, kb, (int)(nqkv / 4));
    k_cvt<<<(int)(nw / 4 / 256), 256, 0, stream>>>(pw, wb, (int)(nw / 4));
    k_vt<<<dim3(NCTX / 64, BATCH * HEADS), 256, 0, stream>>>(v, vt);

    // attention (R5 structure, single-bf16 QK^T)
    k_attn<<<dim3(NCTX / 64, BATCH * HEADS), 256, 0, stream>>>(qb, kb, vt, xb);

    // projection (single-bf16)
    k_proj<<<dim3((BATCH * NCTX) / 64, EMB / 64), 256, 0, stream>>>(xb, wb, pb, out);
}

// Round 8
// 83.656 us; speedup vs baseline: 3.6682x; 1.0080x over previous
//
#include <hip/hip_runtime.h>
#include <cstdint>

typedef short bf16x8 __attribute__((ext_vector_type(8)));
typedef float f32x4 __attribute__((ext_vector_type(4)));
typedef uint16_t u16x4 __attribute__((ext_vector_type(4)));

#define MFMA_16x16x32(a, b, c) __builtin_amdgcn_mfma_f32_16x16x32_bf16((a), (b), (c), 0, 0, 0)

static constexpr int BATCH = 2;
static constexpr int HEADS = 12;
static constexpr int NCTX  = 2048;
static constexpr int DH    = 64;
static constexpr int EMB   = 768;

// 0.125 * log2(e): Q pre-scale so softmax runs in exp2 domain
static constexpr float QSCALE = 0.125f * 1.44269504088896340736f;

// ---------- bf16 helpers (raw-bit, RN rounding) ----------
__device__ __forceinline__ uint16_t f2bf(float x) {
    uint32_t u = __float_as_uint(x);
    u += 0x7FFFu + ((u >> 16) & 1u);
    return (uint16_t)(u >> 16);
}
__device__ __forceinline__ uint32_t cvt_pk_bf16(float lo, float hi) {
    uint32_t r;
    asm("v_cvt_pk_bf16_f32 %0, %1, %2" : "=v"(r) : "v"(lo), "v"(hi));
    return r;
}

// ---------- plain convert (K and W) ----------
__global__ void k_cvt(const float* __restrict__ src, uint16_t* __restrict__ dst, int n4) {
    int i = blockIdx.x * blockDim.x + threadIdx.x;
    if (i >= n4) return;
    float4 v = reinterpret_cast<const float4*>(src)[i];
    u16x4 hv = {f2bf(v.x), f2bf(v.y), f2bf(v.z), f2bf(v.w)};
    reinterpret_cast<u16x4*>(dst)[i] = hv;
}

// ---------- V transpose+convert: [bh][n][64] fp32 -> [bh][64][n] bf16 ----------
__global__ __launch_bounds__(256) void k_vt(const float* __restrict__ v,
                                            uint16_t* __restrict__ vt) {
    const int bh = blockIdx.y;
    const int n0 = blockIdx.x * 64;
    const int t  = threadIdx.x;
    __shared__ uint16_t tileT[64][72];   // [d][n_local]

    const int r  = t >> 2;          // n-row within tile (0..63)
    const int cc = (t & 3) * 16;    // d-col base
    const float* vp = v + ((size_t)bh * NCTX + n0 + r) * DH + cc;
#pragma unroll
    for (int u = 0; u < 4; ++u) {
        float4 x = reinterpret_cast<const float4*>(vp)[u];
        tileT[cc + 4 * u + 0][r] = f2bf(x.x);
        tileT[cc + 4 * u + 1][r] = f2bf(x.y);
        tileT[cc + 4 * u + 2][r] = f2bf(x.z);
        tileT[cc + 4 * u + 3][r] = f2bf(x.w);
    }
    __syncthreads();
    const int d  = t >> 2;          // d-row (0..63)
    const int nc = (t & 3) * 16;    // n chunk
    uint16_t* op = vt + ((size_t)bh * DH + d) * NCTX + n0 + nc;
#pragma unroll
    for (int u = 0; u < 2; ++u) {
        bf16x8 x = *reinterpret_cast<const bf16x8*>(&tileT[d][nc + 8 * u]);
        *reinterpret_cast<bf16x8*>(op + 8 * u) = x;
    }
}

// ---------- flash attention ----------
// grid: (NCTX/64, BATCH*HEADS), block: 256 (4 waves). Wave owns 16 q-rows.
// R7 structure + double-buffered K/V LDS (ONE barrier per tile: read buf[t&1],
// write prefetch to buf[(t+1)&1] after PV, barrier at tile end) + Q converted
// in-prologue from fp32 (k_cvtqk's Q half folded in). Softmax/P/epilogue
// bit-identical to R7.
__global__ __launch_bounds__(256) void k_attn(
        const float* __restrict__ q, const uint16_t* __restrict__ kb,
        const uint16_t* __restrict__ vt, uint16_t* __restrict__ xb) {
    const int bh = blockIdx.y;
    const int b  = bh / HEADS;
    const int h  = bh % HEADS;
    const int tid = threadIdx.x;
    const int w = tid >> 6;
    const int l = tid & 63;
    const int g = l >> 4;    // 16-lane group 0..3
    const int c = l & 15;

    __shared__ uint16_t K_s[2][64][72];
    __shared__ uint16_t V_s[2][64][72];   // [buf][d][kv]
    __shared__ uint16_t P_s[4][16][72];   // [wave][q][kv]

    const int q0 = blockIdx.x * 64 + w * 16;

    // Q fragments: load fp32 direct, scale by 0.125*log2e, convert in-reg
    bf16x8 qa[2];
    {
        const float* qp = q + ((size_t)bh * NCTX + q0 + c) * DH + 8 * g;
#pragma unroll
        for (int kf = 0; kf < 2; ++kf) {
            float4 x0 = *reinterpret_cast<const float4*>(qp + kf * 32);
            float4 x1 = *reinterpret_cast<const float4*>(qp + kf * 32 + 4);
            bf16x8 f;
            f[0] = (short)f2bf(x0.x * QSCALE); f[1] = (short)f2bf(x0.y * QSCALE);
            f[2] = (short)f2bf(x0.z * QSCALE); f[3] = (short)f2bf(x0.w * QSCALE);
            f[4] = (short)f2bf(x1.x * QSCALE); f[5] = (short)f2bf(x1.y * QSCALE);
            f[6] = (short)f2bf(x1.z * QSCALE); f[7] = (short)f2bf(x1.w * QSCALE);
            qa[kf] = f;
        }
    }

    f32x4 zero = {0.f, 0.f, 0.f, 0.f};
    f32x4 o[4] = {zero, zero, zero, zero};
    float m = -1e30f;     // running max (log2 units), per q=c (uniform across groups)
    float lsum = 0.f;     // lane-partial softmax denominator for q=c

    // staging decomposition: 256 thr -> 32 rows x 8 chunks, two row-passes
    const int srow = tid >> 3;      // 0..31
    const int sch  = tid & 7;       // 0..7

    const uint16_t* kb_b = kb + (size_t)bh * NCTX * DH + srow * DH + sch * 8;
    const uint16_t* vt_b = vt + (size_t)bh * DH * NCTX + srow * NCTX + sch * 8;

    // prologue: stage tile 0 into buffer 0
    {
        bf16x8 a0 = *reinterpret_cast<const bf16x8*>(kb_b);
        bf16x8 a1 = *reinterpret_cast<const bf16x8*>(kb_b + 32 * DH);
        bf16x8 v0 = *reinterpret_cast<const bf16x8*>(vt_b);
        bf16x8 v1 = *reinterpret_cast<const bf16x8*>(vt_b + 32 * NCTX);
        *reinterpret_cast<bf16x8*>(&K_s[0][srow][sch * 8])      = a0;
        *reinterpret_cast<bf16x8*>(&K_s[0][srow + 32][sch * 8]) = a1;
        *reinterpret_cast<bf16x8*>(&V_s[0][srow][sch * 8])      = v0;
        *reinterpret_cast<bf16x8*>(&V_s[0][srow + 32][sch * 8]) = v1;
    }
    __syncthreads();

    for (int t = 0; t < NCTX / 64; ++t) {
        const int cur = t & 1;
        const int nxt = cur ^ 1;

        // issue next-tile loads early (hide latency under compute)
        bf16x8 nk0, nk1, nv0, nv1;
        const bool pf = (t + 1) < NCTX / 64;
        if (pf) {
            const size_t ko = (size_t)(t + 1) * 64 * DH;
            const size_t vo = (size_t)(t + 1) * 64;
            nk0 = *reinterpret_cast<const bf16x8*>(kb_b + ko);
            nk1 = *reinterpret_cast<const bf16x8*>(kb_b + ko + 32 * DH);
            nv0 = *reinterpret_cast<const bf16x8*>(vt_b + vo);
            nv1 = *reinterpret_cast<const bf16x8*>(vt_b + vo + 32 * NCTX);
        }

        // ---- S^T = (K Q^T) single-bf16. s[nf][r] = S[kv=16nf+4g+r][q=c]
        f32x4 s[4] = {zero, zero, zero, zero};
        __builtin_amdgcn_s_setprio(1);
#pragma unroll
        for (int nf = 0; nf < 4; ++nf) {
#pragma unroll
            for (int kf = 0; kf < 2; ++kf) {
                bf16x8 bhf = *reinterpret_cast<const bf16x8*>(&K_s[cur][nf * 16 + c][kf * 32 + 8 * g]);
                s[nf] = MFMA_16x16x32(bhf, qa[kf], s[nf]);
            }
        }
        __builtin_amdgcn_s_setprio(0);

        // ---- softmax (log2 domain). Row (per-q) reduce: in-lane + 2 shfls.
        float smax = s[0][0];
#pragma unroll
        for (int nf = 0; nf < 4; ++nf)
#pragma unroll
            for (int r = 0; r < 4; ++r) smax = fmaxf(smax, s[nf][r]);
        smax = fmaxf(smax, __shfl_xor(smax, 16));
        smax = fmaxf(smax, __shfl_xor(smax, 32));

        // deferred max (THR = 11 in log2 units ~= e^8)
        if (!__all(smax <= m + 11.0f)) {
            float mnew = fmaxf(m, smax);
            float corr = __builtin_amdgcn_exp2f(m - mnew);
            m = mnew;
            lsum *= corr;
#pragma unroll
            for (int r = 0; r < 4; ++r) {
                float cr = __shfl(corr, 4 * g + r);   // corr for q-local 4g+r
#pragma unroll
                for (int f = 0; f < 4; ++f) o[f][r] *= cr;
            }
        }

        // p = exp2(s - m); pack pairs and write 4 contiguous kv per lane (b64)
#pragma unroll
        for (int nf = 0; nf < 4; ++nf) {
            float p0 = __builtin_amdgcn_exp2f(s[nf][0] - m);
            float p1 = __builtin_amdgcn_exp2f(s[nf][1] - m);
            float p2 = __builtin_amdgcn_exp2f(s[nf][2] - m);
            float p3 = __builtin_amdgcn_exp2f(s[nf][3] - m);
            lsum += (p0 + p1) + (p2 + p3);
            uint2 pk;
            pk.x = cvt_pk_bf16(p0, p1);
            pk.y = cvt_pk_bf16(p2, p3);
            *reinterpret_cast<uint2*>(&P_s[w][c][16 * nf + 4 * g]) = pk;
        }

        // ---- O += P V (V_s gives contiguous B-fragments)
        bf16x8 pa0 = *reinterpret_cast<const bf16x8*>(&P_s[w][c][8 * g]);
        bf16x8 pa1 = *reinterpret_cast<const bf16x8*>(&P_s[w][c][32 + 8 * g]);
        __builtin_amdgcn_s_setprio(1);
#pragma unroll
        for (int f = 0; f < 4; ++f) {
            bf16x8 b0 = *reinterpret_cast<const bf16x8*>(&V_s[cur][f * 16 + c][8 * g]);
            bf16x8 b1 = *reinterpret_cast<const bf16x8*>(&V_s[cur][f * 16 + c][32 + 8 * g]);
            o[f] = MFMA_16x16x32(pa0, b0, o[f]);
            o[f] = MFMA_16x16x32(pa1, b1, o[f]);
        }
        __builtin_amdgcn_s_setprio(0);

        // ---- write prefetched tile to the ALTERNATE buffer, then single barrier.
        // Writes to buf[nxt] can't race tile-t reads of buf[cur]; the barrier
        // separates tile-t reads of buf[cur] from tile-(t+1) writes into it.
        if (pf) {
            *reinterpret_cast<bf16x8*>(&K_s[nxt][srow][sch * 8])      = nk0;
            *reinterpret_cast<bf16x8*>(&K_s[nxt][srow + 32][sch * 8]) = nk1;
            *reinterpret_cast<bf16x8*>(&V_s[nxt][srow][sch * 8])      = nv0;
            *reinterpret_cast<bf16x8*>(&V_s[nxt][srow + 32][sch * 8]) = nv1;
        }
        __syncthreads();
    }

    // ---- epilogue: reduce l over the 4 groups, normalize, store bf16
    lsum += __shfl_xor(lsum, 16);
    lsum += __shfl_xor(lsum, 32);
    const float linv = 1.0f / lsum;

    const size_t xbase = ((size_t)b * NCTX + q0) * EMB + h * DH;
#pragma unroll
    for (int r = 0; r < 4; ++r) {
        float lr = __shfl(linv, 4 * g + r);   // 1/l for q-local 4g+r
#pragma unroll
        for (int f = 0; f < 4; ++f) {
            float v = o[f][r] * lr;
            size_t addr = xbase + (size_t)(4 * g + r) * EMB + f * 16 + c;
            xb[addr] = f2bf(v);
        }
    }
}

// ---------- projection GEMM: Y[4096x768] = X @ W^T + bias (single-bf16) ----------
// R5 barrier skeleton + clamped-index register prefetch.
__global__ __launch_bounds__(256) void k_proj(
        const uint16_t* __restrict__ xb, const uint16_t* __restrict__ wb,
        const float* __restrict__ bias, float* __restrict__ out) {
    const int tid = threadIdx.x;
    const int w = tid >> 6;
    const int l = tid & 63;
    const int g = l >> 4;
    const int c = l & 15;
    const int m0 = blockIdx.x * 64 + w * 16;
    const int n0 = blockIdx.y * 64;

    __shared__ uint16_t Wh_s[64][40];

    f32x4 zero = {0.f, 0.f, 0.f, 0.f};
    f32x4 acc[4] = {zero, zero, zero, zero};

    const int srow = tid >> 2;   // 0..63
    const int sch  = tid & 3;    // 0..3
    constexpr int KSTEPS = EMB / 32;   // 24

    const uint16_t* whp = wb + (size_t)(n0 + srow) * EMB + sch * 8;
    const uint16_t* xhp = xb + (size_t)(m0 + c) * EMB + 8 * g;

    // prologue loads (k-step 0)
    bf16x8 wldh = *reinterpret_cast<const bf16x8*>(whp);
    bf16x8 ah   = *reinterpret_cast<const bf16x8*>(xhp);

    for (int ks = 0; ks < KSTEPS; ++ks) {
        __syncthreads();     // previous iteration's readers are done (no-op at ks=0)
        *reinterpret_cast<bf16x8*>(&Wh_s[srow][sch * 8]) = wldh;
        __syncthreads();     // stores visible to all waves

        // prefetch next k-step (clamped on the last iteration — always in-bounds,
        // values dead after the final trip)
        const int ksn = (ks + 1 < KSTEPS) ? (ks + 1) : (KSTEPS - 1);
        bf16x8 wldh_n = *reinterpret_cast<const bf16x8*>(whp + (size_t)ksn * 32);
        bf16x8 ah_n   = *reinterpret_cast<const bf16x8*>(xhp + (size_t)ksn * 32);

        __builtin_amdgcn_s_setprio(1);
#pragma unroll
        for (int nf = 0; nf < 4; ++nf) {
            bf16x8 bhf = *reinterpret_cast<const bf16x8*>(&Wh_s[nf * 16 + c][8 * g]);
            acc[nf] = MFMA_16x16x32(ah, bhf, acc[nf]);
        }
        __builtin_amdgcn_s_setprio(0);

        wldh = wldh_n; ah = ah_n;
    }

#pragma unroll
    for (int nf = 0; nf < 4; ++nf) {
#pragma unroll
        for (int r = 0; r < 4; ++r) {
            int row = m0 + g * 4 + r;
            int col = n0 + nf * 16 + c;
            out[(size_t)row * EMB + col] = acc[nf][r] + bias[col];
        }
    }
}

extern "C" void kernel_launch(void* const* d_in, const int* in_sizes, int n_in,
                              void* d_out, int out_size, void* d_ws, size_t ws_size,
                              hipStream_t stream) {
    const float* q    = (const float*)d_in[0];
    const float* k    = (const float*)d_in[1];
    const float* v    = (const float*)d_in[2];
    const float* pw   = (const float*)d_in[3];
    const float* pb   = (const float*)d_in[4];
    float* out = (float*)d_out;

    const size_t nqkv = (size_t)BATCH * HEADS * NCTX * DH;   // 3,145,728
    const size_t nx   = (size_t)BATCH * NCTX * EMB;          // 3,145,728
    const size_t nw   = (size_t)EMB * EMB;                   //   589,824

    uint8_t* ws = (uint8_t*)d_ws;
    uint16_t* kb = (uint16_t*)ws;              ws += nqkv * 2;
    uint16_t* vt = (uint16_t*)ws;              ws += nqkv * 2;
    uint16_t* xb = (uint16_t*)ws;              ws += nx * 2;
    uint16_t* wb = (uint16_t*)ws;              ws += nw * 2;

    // converts (Q handled inside k_attn)
    k_cvt<<<(int)(nqkv / 4 / 256), 256, 0, stream>>>(k, kb, (int)(nqkv / 4));
    k_cvt<<<(int)(nw / 4 / 256),   256, 0, stream>>>(pw, wb, (int)(nw / 4));
    k_vt<<<dim3(NCTX / 64, BATCH * HEADS), 256, 0, stream>>>(v, vt);

    // attention (double-buffered LDS, one barrier per tile, Q folded)
    k_attn<<<dim3(NCTX / 64, BATCH * HEADS), 256, 0, stream>>>(q, kb, vt, xb);

    // projection (single-bf16)
    k_proj<<<dim3((BATCH * NCTX) / 64, EMB / 64), 256, 0, stream>>>(xb, wb, pb, out);
}

// Round 9
// 78.275 us; speedup vs baseline: 3.9204x; 1.0687x over previous
//
#include <hip/hip_runtime.h>
#include <cstdint>

typedef short bf16x8 __attribute__((ext_vector_type(8)));
typedef float f32x4 __attribute__((ext_vector_type(4)));
typedef uint16_t u16x4 __attribute__((ext_vector_type(4)));

#define MFMA_16x16x32(a, b, c) __builtin_amdgcn_mfma_f32_16x16x32_bf16((a), (b), (c), 0, 0, 0)

static constexpr int BATCH = 2;
static constexpr int HEADS = 12;
static constexpr int NCTX  = 2048;
static constexpr int DH    = 64;
static constexpr int EMB   = 768;

// 0.125 * log2(e): Q pre-scale so softmax runs in exp2 domain
static constexpr float QSCALE = 0.125f * 1.44269504088896340736f;

// ---------- bf16 helpers (raw-bit, RN rounding) ----------
__device__ __forceinline__ uint16_t f2bf(float x) {
    uint32_t u = __float_as_uint(x);
    u += 0x7FFFu + ((u >> 16) & 1u);
    return (uint16_t)(u >> 16);
}
__device__ __forceinline__ uint32_t cvt_pk_bf16(float lo, float hi) {
    uint32_t r;
    asm("v_cvt_pk_bf16_f32 %0, %1, %2" : "=v"(r) : "v"(lo), "v"(hi));
    return r;
}

// ---------- merged convert: K (range [0,n4a)) and W (range [n4a,n4a+n4b)) ----------
__global__ void k_cvt2(const float* __restrict__ a, uint16_t* __restrict__ da, int n4a,
                       const float* __restrict__ b2, uint16_t* __restrict__ db, int n4b) {
    int i = blockIdx.x * blockDim.x + threadIdx.x;
    const float* src; uint16_t* dst; int j;
    if (i < n4a) { src = a; dst = da; j = i; }
    else {
        j = i - n4a;
        if (j >= n4b) return;
        src = b2; dst = db;
    }
    float4 v = reinterpret_cast<const float4*>(src)[j];
    u16x4 hv = {f2bf(v.x), f2bf(v.y), f2bf(v.z), f2bf(v.w)};
    reinterpret_cast<u16x4*>(dst)[j] = hv;
}

// ---------- V transpose+convert: [bh][n][64] fp32 -> [bh][64][n] bf16 ----------
__global__ __launch_bounds__(256) void k_vt(const float* __restrict__ v,
                                            uint16_t* __restrict__ vt) {
    const int bh = blockIdx.y;
    const int n0 = blockIdx.x * 64;
    const int t  = threadIdx.x;
    __shared__ uint16_t tileT[64][72];   // [d][n_local]

    const int r  = t >> 2;          // n-row within tile (0..63)
    const int cc = (t & 3) * 16;    // d-col base
    const float* vp = v + ((size_t)bh * NCTX + n0 + r) * DH + cc;
#pragma unroll
    for (int u = 0; u < 4; ++u) {
        float4 x = reinterpret_cast<const float4*>(vp)[u];
        tileT[cc + 4 * u + 0][r] = f2bf(x.x);
        tileT[cc + 4 * u + 1][r] = f2bf(x.y);
        tileT[cc + 4 * u + 2][r] = f2bf(x.z);
        tileT[cc + 4 * u + 3][r] = f2bf(x.w);
    }
    __syncthreads();
    const int d  = t >> 2;          // d-row (0..63)
    const int nc = (t & 3) * 16;    // n chunk
    uint16_t* op = vt + ((size_t)bh * DH + d) * NCTX + n0 + nc;
#pragma unroll
    for (int u = 0; u < 2; ++u) {
        bf16x8 x = *reinterpret_cast<const bf16x8*>(&tileT[d][nc + 8 * u]);
        *reinterpret_cast<bf16x8*>(op + 8 * u) = x;
    }
}

// ---------- flash attention ----------
// R8 structure with shfl-free deferred-max check: the per-tile threshold test
// uses per-lane partial maxes only (provably equivalent: AND over all 64 lanes
// == AND over full row-maxes since m is uniform within each c-group); the
// cross-lane reduce happens only inside the rare rescale branch. fmax chain
// tree-structured (depth 4). Everything else bit-identical to R8.
__global__ __launch_bounds__(256) void k_attn(
        const float* __restrict__ q, const uint16_t* __restrict__ kb,
        const uint16_t* __restrict__ vt, uint16_t* __restrict__ xb) {
    const int bh = blockIdx.y;
    const int b  = bh / HEADS;
    const int h  = bh % HEADS;
    const int tid = threadIdx.x;
    const int w = tid >> 6;
    const int l = tid & 63;
    const int g = l >> 4;    // 16-lane group 0..3
    const int c = l & 15;

    __shared__ uint16_t K_s[2][64][72];
    __shared__ uint16_t V_s[2][64][72];   // [buf][d][kv]
    __shared__ uint16_t P_s[4][16][72];   // [wave][q][kv]

    const int q0 = blockIdx.x * 64 + w * 16;

    // Q fragments: load fp32 direct, scale by 0.125*log2e, convert in-reg
    bf16x8 qa[2];
    {
        const float* qp = q + ((size_t)bh * NCTX + q0 + c) * DH + 8 * g;
#pragma unroll
        for (int kf = 0; kf < 2; ++kf) {
            float4 x0 = *reinterpret_cast<const float4*>(qp + kf * 32);
            float4 x1 = *reinterpret_cast<const float4*>(qp + kf * 32 + 4);
            bf16x8 f;
            f[0] = (short)f2bf(x0.x * QSCALE); f[1] = (short)f2bf(x0.y * QSCALE);
            f[2] = (short)f2bf(x0.z * QSCALE); f[3] = (short)f2bf(x0.w * QSCALE);
            f[4] = (short)f2bf(x1.x * QSCALE); f[5] = (short)f2bf(x1.y * QSCALE);
            f[6] = (short)f2bf(x1.z * QSCALE); f[7] = (short)f2bf(x1.w * QSCALE);
            qa[kf] = f;
        }
    }

    f32x4 zero = {0.f, 0.f, 0.f, 0.f};
    f32x4 o[4] = {zero, zero, zero, zero};
    float m = -1e30f;     // running max (log2 units), per q=c (uniform across groups)
    float lsum = 0.f;     // lane-partial softmax denominator for q=c

    // staging decomposition: 256 thr -> 32 rows x 8 chunks, two row-passes
    const int srow = tid >> 3;      // 0..31
    const int sch  = tid & 7;       // 0..7

    const uint16_t* kb_b = kb + (size_t)bh * NCTX * DH + srow * DH + sch * 8;
    const uint16_t* vt_b = vt + (size_t)bh * DH * NCTX + srow * NCTX + sch * 8;

    // prologue: stage tile 0 into buffer 0
    {
        bf16x8 a0 = *reinterpret_cast<const bf16x8*>(kb_b);
        bf16x8 a1 = *reinterpret_cast<const bf16x8*>(kb_b + 32 * DH);
        bf16x8 v0 = *reinterpret_cast<const bf16x8*>(vt_b);
        bf16x8 v1 = *reinterpret_cast<const bf16x8*>(vt_b + 32 * NCTX);
        *reinterpret_cast<bf16x8*>(&K_s[0][srow][sch * 8])      = a0;
        *reinterpret_cast<bf16x8*>(&K_s[0][srow + 32][sch * 8]) = a1;
        *reinterpret_cast<bf16x8*>(&V_s[0][srow][sch * 8])      = v0;
        *reinterpret_cast<bf16x8*>(&V_s[0][srow + 32][sch * 8]) = v1;
    }
    __syncthreads();

    for (int t = 0; t < NCTX / 64; ++t) {
        const int cur = t & 1;
        const int nxt = cur ^ 1;

        // issue next-tile loads early (hide latency under compute)
        bf16x8 nk0, nk1, nv0, nv1;
        const bool pf = (t + 1) < NCTX / 64;
        if (pf) {
            const size_t ko = (size_t)(t + 1) * 64 * DH;
            const size_t vo = (size_t)(t + 1) * 64;
            nk0 = *reinterpret_cast<const bf16x8*>(kb_b + ko);
            nk1 = *reinterpret_cast<const bf16x8*>(kb_b + ko + 32 * DH);
            nv0 = *reinterpret_cast<const bf16x8*>(vt_b + vo);
            nv1 = *reinterpret_cast<const bf16x8*>(vt_b + vo + 32 * NCTX);
        }

        // ---- S^T = (K Q^T) single-bf16. s[nf][r] = S[kv=16nf+4g+r][q=c]
        f32x4 s[4] = {zero, zero, zero, zero};
        __builtin_amdgcn_s_setprio(1);
#pragma unroll
        for (int nf = 0; nf < 4; ++nf) {
#pragma unroll
            for (int kf = 0; kf < 2; ++kf) {
                bf16x8 bhf = *reinterpret_cast<const bf16x8*>(&K_s[cur][nf * 16 + c][kf * 32 + 8 * g]);
                s[nf] = MFMA_16x16x32(bhf, qa[kf], s[nf]);
            }
        }
        __builtin_amdgcn_s_setprio(0);

        // ---- per-lane partial max over this lane's 16 kv slots (tree, depth 4)
        float pm0 = fmaxf(fmaxf(s[0][0], s[0][1]), fmaxf(s[0][2], s[0][3]));
        float pm1 = fmaxf(fmaxf(s[1][0], s[1][1]), fmaxf(s[1][2], s[1][3]));
        float pm2 = fmaxf(fmaxf(s[2][0], s[2][1]), fmaxf(s[2][2], s[2][3]));
        float pm3 = fmaxf(fmaxf(s[3][0], s[3][1]), fmaxf(s[3][2], s[3][3]));
        float pmax = fmaxf(fmaxf(pm0, pm1), fmaxf(pm2, pm3));

        // deferred max, shfl-free common path: __all over per-lane partials is
        // equivalent to __all over row-maxes (m uniform within each c-group).
        if (!__all(pmax <= m + 11.0f)) {
            float smax = fmaxf(pmax, __shfl_xor(pmax, 16));
            smax = fmaxf(smax, __shfl_xor(smax, 32));
            float mnew = fmaxf(m, smax);
            float corr = __builtin_amdgcn_exp2f(m - mnew);
            m = mnew;
            lsum *= corr;
#pragma unroll
            for (int r = 0; r < 4; ++r) {
                float cr = __shfl(corr, 4 * g + r);   // corr for q-local 4g+r
#pragma unroll
                for (int f = 0; f < 4; ++f) o[f][r] *= cr;
            }
        }

        // p = exp2(s - m); pack pairs and write 4 contiguous kv per lane (b64)
#pragma unroll
        for (int nf = 0; nf < 4; ++nf) {
            float p0 = __builtin_amdgcn_exp2f(s[nf][0] - m);
            float p1 = __builtin_amdgcn_exp2f(s[nf][1] - m);
            float p2 = __builtin_amdgcn_exp2f(s[nf][2] - m);
            float p3 = __builtin_amdgcn_exp2f(s[nf][3] - m);
            lsum += (p0 + p1) + (p2 + p3);
            uint2 pk;
            pk.x = cvt_pk_bf16(p0, p1);
            pk.y = cvt_pk_bf16(p2, p3);
            *reinterpret_cast<uint2*>(&P_s[w][c][16 * nf + 4 * g]) = pk;
        }

        // ---- O += P V (V_s gives contiguous B-fragments)
        bf16x8 pa0 = *reinterpret_cast<const bf16x8*>(&P_s[w][c][8 * g]);
        bf16x8 pa1 = *reinterpret_cast<const bf16x8*>(&P_s[w][c][32 + 8 * g]);
        __builtin_amdgcn_s_setprio(1);
#pragma unroll
        for (int f = 0; f < 4; ++f) {
            bf16x8 b0 = *reinterpret_cast<const bf16x8*>(&V_s[cur][f * 16 + c][8 * g]);
            bf16x8 b1 = *reinterpret_cast<const bf16x8*>(&V_s[cur][f * 16 + c][32 + 8 * g]);
            o[f] = MFMA_16x16x32(pa0, b0, o[f]);
            o[f] = MFMA_16x16x32(pa1, b1, o[f]);
        }
        __builtin_amdgcn_s_setprio(0);

        // ---- write prefetched tile to the ALTERNATE buffer, then single barrier.
        if (pf) {
            *reinterpret_cast<bf16x8*>(&K_s[nxt][srow][sch * 8])      = nk0;
            *reinterpret_cast<bf16x8*>(&K_s[nxt][srow + 32][sch * 8]) = nk1;
            *reinterpret_cast<bf16x8*>(&V_s[nxt][srow][sch * 8])      = nv0;
            *reinterpret_cast<bf16x8*>(&V_s[nxt][srow + 32][sch * 8]) = nv1;
        }
        __syncthreads();
    }

    // ---- epilogue: reduce l over the 4 groups, normalize, store bf16
    lsum += __shfl_xor(lsum, 16);
    lsum += __shfl_xor(lsum, 32);
    const float linv = 1.0f / lsum;

    const size_t xbase = ((size_t)b * NCTX + q0) * EMB + h * DH;
#pragma unroll
    for (int r = 0; r < 4; ++r) {
        float lr = __shfl(linv, 4 * g + r);   // 1/l for q-local 4g+r
#pragma unroll
        for (int f = 0; f < 4; ++f) {
            float v = o[f][r] * lr;
            size_t addr = xbase + (size_t)(4 * g + r) * EMB + f * 16 + c;
            xb[addr] = f2bf(v);
        }
    }
}

// ---------- projection GEMM: Y[4096x768] = X @ W^T + bias (single-bf16) ----------
// 64-wide k rounds: 2 k-steps staged per barrier pair (12 rounds, 8 MFMA/round),
// clamped-index register prefetch. Same accumulate order as R8 (bit-identical).
__global__ __launch_bounds__(256) void k_proj(
        const uint16_t* __restrict__ xb, const uint16_t* __restrict__ wb,
        const float* __restrict__ bias, float* __restrict__ out) {
    const int tid = threadIdx.x;
    const int w = tid >> 6;
    const int l = tid & 63;
    const int g = l >> 4;
    const int c = l & 15;
    const int m0 = blockIdx.x * 64 + w * 16;
    const int n0 = blockIdx.y * 64;

    __shared__ uint16_t W_s[64][72];

    f32x4 zero = {0.f, 0.f, 0.f, 0.f};
    f32x4 acc[4] = {zero, zero, zero, zero};

    const int srow = tid >> 2;   // 0..63
    const int sch  = tid & 3;    // 0..3
    constexpr int ROUNDS = EMB / 64;   // 12

    const uint16_t* whp = wb + (size_t)(n0 + srow) * EMB + sch * 8;
    const uint16_t* xhp = xb + (size_t)(m0 + c) * EMB + 8 * g;

    // prologue loads (round 0): two 32-wide k-chunks each
    bf16x8 w0 = *reinterpret_cast<const bf16x8*>(whp);
    bf16x8 w1 = *reinterpret_cast<const bf16x8*>(whp + 32);
    bf16x8 a0 = *reinterpret_cast<const bf16x8*>(xhp);
    bf16x8 a1 = *reinterpret_cast<const bf16x8*>(xhp + 32);

    for (int rd = 0; rd < ROUNDS; ++rd) {
        __syncthreads();     // previous round's readers done (no-op at rd=0)
        *reinterpret_cast<bf16x8*>(&W_s[srow][sch * 8])      = w0;
        *reinterpret_cast<bf16x8*>(&W_s[srow][32 + sch * 8]) = w1;
        __syncthreads();     // stores visible

        // prefetch next round (clamped on last iteration — always in-bounds,
        // values dead after the final trip)
        const int rn = (rd + 1 < ROUNDS) ? (rd + 1) : (ROUNDS - 1);
        bf16x8 w0n = *reinterpret_cast<const bf16x8*>(whp + (size_t)rn * 64);
        bf16x8 w1n = *reinterpret_cast<const bf16x8*>(whp + (size_t)rn * 64 + 32);
        bf16x8 a0n = *reinterpret_cast<const bf16x8*>(xhp + (size_t)rn * 64);
        bf16x8 a1n = *reinterpret_cast<const bf16x8*>(xhp + (size_t)rn * 64 + 32);

        __builtin_amdgcn_s_setprio(1);
#pragma unroll
        for (int nf = 0; nf < 4; ++nf) {
            bf16x8 b0 = *reinterpret_cast<const bf16x8*>(&W_s[nf * 16 + c][8 * g]);
            bf16x8 b1 = *reinterpret_cast<const bf16x8*>(&W_s[nf * 16 + c][32 + 8 * g]);
            acc[nf] = MFMA_16x16x32(a0, b0, acc[nf]);
            acc[nf] = MFMA_16x16x32(a1, b1, acc[nf]);
        }
        __builtin_amdgcn_s_setprio(0);

        w0 = w0n; w1 = w1n; a0 = a0n; a1 = a1n;
    }

#pragma unroll
    for (int nf = 0; nf < 4; ++nf) {
#pragma unroll
        for (int r = 0; r < 4; ++r) {
            int row = m0 + g * 4 + r;
            int col = n0 + nf * 16 + c;
            out[(size_t)row * EMB + col] = acc[nf][r] + bias[col];
        }
    }
}

extern "C" void kernel_launch(void* const* d_in, const int* in_sizes, int n_in,
                              void* d_out, int out_size, void* d_ws, size_t ws_size,
                              hipStream_t stream) {
    const float* q    = (const float*)d_in[0];
    const float* k    = (const float*)d_in[1];
    const float* v    = (const float*)d_in[2];
    const float* pw   = (const float*)d_in[3];
    const float* pb   = (const float*)d_in[4];
    float* out = (float*)d_out;

    const size_t nqkv = (size_t)BATCH * HEADS * NCTX * DH;   // 3,145,728
    const size_t nx   = (size_t)BATCH * NCTX * EMB;          // 3,145,728
    const size_t nw   = (size_t)EMB * EMB;                   //   589,824

    uint8_t* ws = (uint8_t*)d_ws;
    uint16_t* kb = (uint16_t*)ws;              ws += nqkv * 2;
    uint16_t* vt = (uint16_t*)ws;              ws += nqkv * 2;
    uint16_t* xb = (uint16_t*)ws;              ws += nx * 2;
    uint16_t* wb = (uint16_t*)ws;              ws += nw * 2;

    // converts: K + W merged into one launch (Q handled inside k_attn)
    const int n4k = (int)(nqkv / 4);
    const int n4w = (int)(nw / 4);
    k_cvt2<<<(n4k + n4w + 255) / 256, 256, 0, stream>>>(k, kb, n4k, pw, wb, n4w);
    k_vt<<<dim3(NCTX / 64, BATCH * HEADS), 256, 0, stream>>>(v, vt);

    // attention (shfl-free defer check, tree max)
    k_attn<<<dim3(NCTX / 64, BATCH * HEADS), 256, 0, stream>>>(q, kb, vt, xb);

    // projection (64-wide k rounds)
    k_proj<<<dim3((BATCH * NCTX) / 64, EMB / 64), 256, 0, stream>>>(xb, wb, pb, out);
}

// Round 10
// 77.590 us; speedup vs baseline: 3.9550x; 1.0088x over previous
//
#include <hip/hip_runtime.h>
#include <cstdint>

typedef short bf16x8 __attribute__((ext_vector_type(8)));
typedef float f32x4 __attribute__((ext_vector_type(4)));
typedef uint16_t u16x4 __attribute__((ext_vector_type(4)));

#define MFMA_16x16x32(a, b, c) __builtin_amdgcn_mfma_f32_16x16x32_bf16((a), (b), (c), 0, 0, 0)

static constexpr int BATCH = 2;
static constexpr int HEADS = 12;
static constexpr int NCTX  = 2048;
static constexpr int DH    = 64;
static constexpr int EMB   = 768;

// 0.125 * log2(e): Q pre-scale so softmax runs in exp2 domain
static constexpr float QSCALE = 0.125f * 1.44269504088896340736f;

// ---------- bf16 helpers (raw-bit, RN rounding) ----------
__device__ __forceinline__ uint16_t f2bf(float x) {
    uint32_t u = __float_as_uint(x);
    u += 0x7FFFu + ((u >> 16) & 1u);
    return (uint16_t)(u >> 16);
}
__device__ __forceinline__ uint32_t cvt_pk_bf16(float lo, float hi) {
    uint32_t r;
    asm("v_cvt_pk_bf16_f32 %0, %1, %2" : "=v"(r) : "v"(lo), "v"(hi));
    return r;
}

// ---------- merged convert: K (range [0,n4a)) and W (range [n4a,n4a+n4b)) ----------
__global__ void k_cvt2(const float* __restrict__ a, uint16_t* __restrict__ da, int n4a,
                       const float* __restrict__ b2, uint16_t* __restrict__ db, int n4b) {
    int i = blockIdx.x * blockDim.x + threadIdx.x;
    const float* src; uint16_t* dst; int j;
    if (i < n4a) { src = a; dst = da; j = i; }
    else {
        j = i - n4a;
        if (j >= n4b) return;
        src = b2; dst = db;
    }
    float4 v = reinterpret_cast<const float4*>(src)[j];
    u16x4 hv = {f2bf(v.x), f2bf(v.y), f2bf(v.z), f2bf(v.w)};
    reinterpret_cast<u16x4*>(dst)[j] = hv;
}

// ---------- V transpose+convert to PV-fragment layout ----------
// vf[((bh*32 + t)*8 + slot)*512 + l*8 + j] = V[kv=64t+32h+8g+j][d=16f+c]
// where slot=2f+h, l=16g+c. Each k_attn B-fragment load is then one fully
// coalesced 1KB instruction: vf + (t*8+slot)*1024B + l*16B.
__global__ __launch_bounds__(256) void k_vt(const float* __restrict__ v,
                                            uint16_t* __restrict__ vt) {
    const int bh = blockIdx.y;
    const int n0 = blockIdx.x * 64;
    const int t  = threadIdx.x;
    __shared__ uint16_t tileT[64][72];   // [d][n_local]

    const int r  = t >> 2;          // n-row within tile (0..63)
    const int cc = (t & 3) * 16;    // d-col base
    const float* vp = v + ((size_t)bh * NCTX + n0 + r) * DH + cc;
#pragma unroll
    for (int u = 0; u < 4; ++u) {
        float4 x = reinterpret_cast<const float4*>(vp)[u];
        tileT[cc + 4 * u + 0][r] = f2bf(x.x);
        tileT[cc + 4 * u + 1][r] = f2bf(x.y);
        tileT[cc + 4 * u + 2][r] = f2bf(x.z);
        tileT[cc + 4 * u + 3][r] = f2bf(x.w);
    }
    __syncthreads();

    const int l2 = t & 63;          // fragment lane
    const int s0 = t >> 6;          // 0..3
    const int gg = l2 >> 4;
    const int c2 = l2 & 15;
    uint16_t* vb = vt + ((size_t)bh * 32 + (n0 >> 6)) * 8 * 512;
#pragma unroll
    for (int u = 0; u < 2; ++u) {
        const int slot = s0 + 4 * u;        // 0..7
        const int f = slot >> 1, h = slot & 1;
        bf16x8 x = *reinterpret_cast<const bf16x8*>(&tileT[f * 16 + c2][h * 32 + 8 * gg]);
        *reinterpret_cast<bf16x8*>(vb + (size_t)slot * 512 + l2 * 8) = x;
    }
}

// ---------- flash attention ----------
// R9 structure with V moved from LDS to registers: 8 coalesced 1KB fragment
// loads per tile, issued at TILE START (~full tile of latency cover before PV
// consumes them). V staging and V LDS reads removed; K path, softmax, P, and
// epilogue byte-identical to R9.
__global__ __launch_bounds__(256) void k_attn(
        const float* __restrict__ q, const uint16_t* __restrict__ kb,
        const uint16_t* __restrict__ vf, uint16_t* __restrict__ xb) {
    const int bh = blockIdx.y;
    const int b  = bh / HEADS;
    const int h  = bh % HEADS;
    const int tid = threadIdx.x;
    const int w = tid >> 6;
    const int l = tid & 63;
    const int g = l >> 4;    // 16-lane group 0..3
    const int c = l & 15;

    __shared__ uint16_t K_s[2][64][72];
    __shared__ uint16_t P_s[4][16][72];   // [wave][q][kv]

    const int q0 = blockIdx.x * 64 + w * 16;

    // Q fragments: load fp32 direct, scale by 0.125*log2e, convert in-reg
    bf16x8 qa[2];
    {
        const float* qp = q + ((size_t)bh * NCTX + q0 + c) * DH + 8 * g;
#pragma unroll
        for (int kf = 0; kf < 2; ++kf) {
            float4 x0 = *reinterpret_cast<const float4*>(qp + kf * 32);
            float4 x1 = *reinterpret_cast<const float4*>(qp + kf * 32 + 4);
            bf16x8 f;
            f[0] = (short)f2bf(x0.x * QSCALE); f[1] = (short)f2bf(x0.y * QSCALE);
            f[2] = (short)f2bf(x0.z * QSCALE); f[3] = (short)f2bf(x0.w * QSCALE);
            f[4] = (short)f2bf(x1.x * QSCALE); f[5] = (short)f2bf(x1.y * QSCALE);
            f[6] = (short)f2bf(x1.z * QSCALE); f[7] = (short)f2bf(x1.w * QSCALE);
            qa[kf] = f;
        }
    }

    f32x4 zero = {0.f, 0.f, 0.f, 0.f};
    f32x4 o[4] = {zero, zero, zero, zero};
    float m = -1e30f;     // running max (log2 units), per q=c (uniform across groups)
    float lsum = 0.f;     // lane-partial softmax denominator for q=c

    // K staging decomposition: 256 thr -> 32 rows x 8 chunks, two row-passes
    const int srow = tid >> 3;      // 0..31
    const int sch  = tid & 7;       // 0..7

    const uint16_t* kb_b = kb + (size_t)bh * NCTX * DH + srow * DH + sch * 8;
    // per-lane V fragment base: vf + bh*32*8*512 + l*8  (advance by (t*8+s)*512)
    const uint16_t* vf_b = vf + (size_t)bh * 32 * 8 * 512 + (size_t)l * 8;

    // prologue: stage K tile 0 into buffer 0
    {
        bf16x8 a0 = *reinterpret_cast<const bf16x8*>(kb_b);
        bf16x8 a1 = *reinterpret_cast<const bf16x8*>(kb_b + 32 * DH);
        *reinterpret_cast<bf16x8*>(&K_s[0][srow][sch * 8])      = a0;
        *reinterpret_cast<bf16x8*>(&K_s[0][srow + 32][sch * 8]) = a1;
    }
    __syncthreads();

    for (int t = 0; t < NCTX / 64; ++t) {
        const int cur = t & 1;
        const int nxt = cur ^ 1;

        // issue next-K-tile loads early (hide latency under compute)
        bf16x8 nk0, nk1;
        const bool pf = (t + 1) < NCTX / 64;
        if (pf) {
            const size_t ko = (size_t)(t + 1) * 64 * DH;
            nk0 = *reinterpret_cast<const bf16x8*>(kb_b + ko);
            nk1 = *reinterpret_cast<const bf16x8*>(kb_b + ko + 32 * DH);
        }

        // issue THIS tile's V fragment loads now (consumed at PV, ~full tile away)
        bf16x8 vr[8];
#pragma unroll
        for (int s = 0; s < 8; ++s)
            vr[s] = *reinterpret_cast<const bf16x8*>(vf_b + ((size_t)t * 8 + s) * 512);

        // ---- S^T = (K Q^T) single-bf16. s[nf][r] = S[kv=16nf+4g+r][q=c]
        f32x4 s[4] = {zero, zero, zero, zero};
        __builtin_amdgcn_s_setprio(1);
#pragma unroll
        for (int nf = 0; nf < 4; ++nf) {
#pragma unroll
            for (int kf = 0; kf < 2; ++kf) {
                bf16x8 bhf = *reinterpret_cast<const bf16x8*>(&K_s[cur][nf * 16 + c][kf * 32 + 8 * g]);
                s[nf] = MFMA_16x16x32(bhf, qa[kf], s[nf]);
            }
        }
        __builtin_amdgcn_s_setprio(0);

        // ---- per-lane partial max over this lane's 16 kv slots (tree, depth 4)
        float pm0 = fmaxf(fmaxf(s[0][0], s[0][1]), fmaxf(s[0][2], s[0][3]));
        float pm1 = fmaxf(fmaxf(s[1][0], s[1][1]), fmaxf(s[1][2], s[1][3]));
        float pm2 = fmaxf(fmaxf(s[2][0], s[2][1]), fmaxf(s[2][2], s[2][3]));
        float pm3 = fmaxf(fmaxf(s[3][0], s[3][1]), fmaxf(s[3][2], s[3][3]));
        float pmax = fmaxf(fmaxf(pm0, pm1), fmaxf(pm2, pm3));

        // deferred max, shfl-free common path (equivalent: see R9)
        if (!__all(pmax <= m + 11.0f)) {
            float smax = fmaxf(pmax, __shfl_xor(pmax, 16));
            smax = fmaxf(smax, __shfl_xor(smax, 32));
            float mnew = fmaxf(m, smax);
            float corr = __builtin_amdgcn_exp2f(m - mnew);
            m = mnew;
            lsum *= corr;
#pragma unroll
            for (int r = 0; r < 4; ++r) {
                float cr = __shfl(corr, 4 * g + r);   // corr for q-local 4g+r
#pragma unroll
                for (int f = 0; f < 4; ++f) o[f][r] *= cr;
            }
        }

        // p = exp2(s - m); pack pairs and write 4 contiguous kv per lane (b64)
#pragma unroll
        for (int nf = 0; nf < 4; ++nf) {
            float p0 = __builtin_amdgcn_exp2f(s[nf][0] - m);
            float p1 = __builtin_amdgcn_exp2f(s[nf][1] - m);
            float p2 = __builtin_amdgcn_exp2f(s[nf][2] - m);
            float p3 = __builtin_amdgcn_exp2f(s[nf][3] - m);
            lsum += (p0 + p1) + (p2 + p3);
            uint2 pk;
            pk.x = cvt_pk_bf16(p0, p1);
            pk.y = cvt_pk_bf16(p2, p3);
            *reinterpret_cast<uint2*>(&P_s[w][c][16 * nf + 4 * g]) = pk;
        }

        // ---- O += P V (V fragments already in registers)
        bf16x8 pa0 = *reinterpret_cast<const bf16x8*>(&P_s[w][c][8 * g]);
        bf16x8 pa1 = *reinterpret_cast<const bf16x8*>(&P_s[w][c][32 + 8 * g]);
        __builtin_amdgcn_s_setprio(1);
#pragma unroll
        for (int f = 0; f < 4; ++f) {
            o[f] = MFMA_16x16x32(pa0, vr[2 * f],     o[f]);
            o[f] = MFMA_16x16x32(pa1, vr[2 * f + 1], o[f]);
        }
        __builtin_amdgcn_s_setprio(0);

        // ---- write prefetched K tile to the ALTERNATE buffer, then one barrier
        if (pf) {
            *reinterpret_cast<bf16x8*>(&K_s[nxt][srow][sch * 8])      = nk0;
            *reinterpret_cast<bf16x8*>(&K_s[nxt][srow + 32][sch * 8]) = nk1;
        }
        __syncthreads();
    }

    // ---- epilogue: reduce l over the 4 groups, normalize, store bf16
    lsum += __shfl_xor(lsum, 16);
    lsum += __shfl_xor(lsum, 32);
    const float linv = 1.0f / lsum;

    const size_t xbase = ((size_t)b * NCTX + q0) * EMB + h * DH;
#pragma unroll
    for (int r = 0; r < 4; ++r) {
        float lr = __shfl(linv, 4 * g + r);   // 1/l for q-local 4g+r
#pragma unroll
        for (int f = 0; f < 4; ++f) {
            float v = o[f][r] * lr;
            size_t addr = xbase + (size_t)(4 * g + r) * EMB + f * 16 + c;
            xb[addr] = f2bf(v);
        }
    }
}

// ---------- projection GEMM: Y[4096x768] = X @ W^T + bias (single-bf16) ----------
// 64-wide k rounds, clamped-index register prefetch (R9, unchanged).
__global__ __launch_bounds__(256) void k_proj(
        const uint16_t* __restrict__ xb, const uint16_t* __restrict__ wb,
        const float* __restrict__ bias, float* __restrict__ out) {
    const int tid = threadIdx.x;
    const int w = tid >> 6;
    const int l = tid & 63;
    const int g = l >> 4;
    const int c = l & 15;
    const int m0 = blockIdx.x * 64 + w * 16;
    const int n0 = blockIdx.y * 64;

    __shared__ uint16_t W_s[64][72];

    f32x4 zero = {0.f, 0.f, 0.f, 0.f};
    f32x4 acc[4] = {zero, zero, zero, zero};

    const int srow = tid >> 2;   // 0..63
    const int sch  = tid & 3;    // 0..3
    constexpr int ROUNDS = EMB / 64;   // 12

    const uint16_t* whp = wb + (size_t)(n0 + srow) * EMB + sch * 8;
    const uint16_t* xhp = xb + (size_t)(m0 + c) * EMB + 8 * g;

    // prologue loads (round 0): two 32-wide k-chunks each
    bf16x8 w0 = *reinterpret_cast<const bf16x8*>(whp);
    bf16x8 w1 = *reinterpret_cast<const bf16x8*>(whp + 32);
    bf16x8 a0 = *reinterpret_cast<const bf16x8*>(xhp);
    bf16x8 a1 = *reinterpret_cast<const bf16x8*>(xhp + 32);

    for (int rd = 0; rd < ROUNDS; ++rd) {
        __syncthreads();     // previous round's readers done (no-op at rd=0)
        *reinterpret_cast<bf16x8*>(&W_s[srow][sch * 8])      = w0;
        *reinterpret_cast<bf16x8*>(&W_s[srow][32 + sch * 8]) = w1;
        __syncthreads();     // stores visible

        // prefetch next round (clamped on last iteration — always in-bounds,
        // values dead after the final trip)
        const int rn = (rd + 1 < ROUNDS) ? (rd + 1) : (ROUNDS - 1);
        bf16x8 w0n = *reinterpret_cast<const bf16x8*>(whp + (size_t)rn * 64);
        bf16x8 w1n = *reinterpret_cast<const bf16x8*>(whp + (size_t)rn * 64 + 32);
        bf16x8 a0n = *reinterpret_cast<const bf16x8*>(xhp + (size_t)rn * 64);
        bf16x8 a1n = *reinterpret_cast<const bf16x8*>(xhp + (size_t)rn * 64 + 32);

        __builtin_amdgcn_s_setprio(1);
#pragma unroll
        for (int nf = 0; nf < 4; ++nf) {
            bf16x8 b0 = *reinterpret_cast<const bf16x8*>(&W_s[nf * 16 + c][8 * g]);
            bf16x8 b1 = *reinterpret_cast<const bf16x8*>(&W_s[nf * 16 + c][32 + 8 * g]);
            acc[nf] = MFMA_16x16x32(a0, b0, acc[nf]);
            acc[nf] = MFMA_16x16x32(a1, b1, acc[nf]);
        }
        __builtin_amdgcn_s_setprio(0);

        w0 = w0n; w1 = w1n; a0 = a0n; a1 = a1n;
    }

#pragma unroll
    for (int nf = 0; nf < 4; ++nf) {
#pragma unroll
        for (int r = 0; r < 4; ++r) {
            int row = m0 + g * 4 + r;
            int col = n0 + nf * 16 + c;
            out[(size_t)row * EMB + col] = acc[nf][r] + bias[col];
        }
    }
}

extern "C" void kernel_launch(void* const* d_in, const int* in_sizes, int n_in,
                              void* d_out, int out_size, void* d_ws, size_t ws_size,
                              hipStream_t stream) {
    const float* q    = (const float*)d_in[0];
    const float* k    = (const float*)d_in[1];
    const float* v    = (const float*)d_in[2];
    const float* pw   = (const float*)d_in[3];
    const float* pb   = (const float*)d_in[4];
    float* out = (float*)d_out;

    const size_t nqkv = (size_t)BATCH * HEADS * NCTX * DH;   // 3,145,728
    const size_t nx   = (size_t)BATCH * NCTX * EMB;          // 3,145,728
    const size_t nw   = (size_t)EMB * EMB;                   //   589,824

    uint8_t* ws = (uint8_t*)d_ws;
    uint16_t* kb = (uint16_t*)ws;              ws += nqkv * 2;
    uint16_t* vf = (uint16_t*)ws;              ws += nqkv * 2;   // fragment layout, same size
    uint16_t* xb = (uint16_t*)ws;              ws += nx * 2;
    uint16_t* wb = (uint16_t*)ws;              ws += nw * 2;

    // converts: K + W merged into one launch (Q handled inside k_attn)
    const int n4k = (int)(nqkv / 4);
    const int n4w = (int)(nw / 4);
    k_cvt2<<<(n4k + n4w + 255) / 256, 256, 0, stream>>>(k, kb, n4k, pw, wb, n4w);
    k_vt<<<dim3(NCTX / 64, BATCH * HEADS), 256, 0, stream>>>(v, vf);

    // attention (V in registers via fragment-contiguous layout)
    k_attn<<<dim3(NCTX / 64, BATCH * HEADS), 256, 0, stream>>>(q, kb, vf, xb);

    // projection (64-wide k rounds)
    k_proj<<<dim3((BATCH * NCTX) / 64, EMB / 64), 256, 0, stream>>>(xb, wb, pb, out);
}